// Round 2
// baseline (579.720 us; speedup 1.0000x reference)
//
#include <hip/hip_runtime.h>
#include <stdint.h>

#define NN 50000
#define NE 800000
#define DD 128
#define NL 3

// ---------- CSR build ----------
__global__ void k_count(const int* __restrict__ dst, int* __restrict__ counts){
  int e = blockIdx.x * 256 + threadIdx.x;
  if (e < NE) atomicAdd(&counts[dst[e]], 1);
}

__global__ void k_scan1(const int* __restrict__ counts, int* __restrict__ offs,
                        int* __restrict__ bsum){
  __shared__ int s[256];
  int t = threadIdx.x; int i = blockIdx.x * 256 + t;
  int v = (i < NN) ? counts[i] : 0;
  s[t] = v; __syncthreads();
  for (int d = 1; d < 256; d <<= 1){
    int x = (t >= d) ? s[t - d] : 0;
    __syncthreads();
    s[t] += x;
    __syncthreads();
  }
  if (i < NN) offs[i] = s[t] - v;           // exclusive
  if (t == 255) bsum[blockIdx.x] = s[255];  // block total
}

__global__ void k_scan2(int* __restrict__ bsum, int nblk){
  __shared__ int s[256];
  int t = threadIdx.x;
  int v = (t < nblk) ? bsum[t] : 0;
  s[t] = v; __syncthreads();
  for (int d = 1; d < 256; d <<= 1){
    int x = (t >= d) ? s[t - d] : 0;
    __syncthreads();
    s[t] += x;
    __syncthreads();
  }
  if (t < nblk) bsum[t] = s[t] - v;         // exclusive, in place
}

__global__ void k_scan3(int* __restrict__ offs, const int* __restrict__ bsum,
                        int* __restrict__ cursor){
  int i = blockIdx.x * 256 + threadIdx.x;
  if (i < NN){
    int o = offs[i] + bsum[blockIdx.x];
    offs[i] = o;
    cursor[i] = o;
  }
}

__global__ void k_fill(const int* __restrict__ src, const int* __restrict__ dst,
                       int* __restrict__ cursor, int* __restrict__ csr_src){
  int e = blockIdx.x * 256 + threadIdx.x;
  if (e < NE){
    int d = dst[e];
    int p = atomicAdd(&cursor[d], 1);
    csr_src[p] = src[e];
  }
}

// ---------- aggregate: out[v] = h[v] + sum_{e: dst==v} h[src[e]] ----------
__global__ __launch_bounds__(256) void k_agg(const float* __restrict__ h,
    const int* __restrict__ offs, const int* __restrict__ counts,
    const int* __restrict__ csr_src, float* __restrict__ out){
  int t = blockIdx.x * 256 + threadIdx.x;
  int row = t >> 5;
  int lane = t & 31;
  if (row >= NN) return;
  const float4* h4 = (const float4*)h;
  float4 acc = h4[row * 32 + lane];            // self term (GIN eps=0)
  int e = offs[row];
  int end = e + counts[row];
  for (; e + 4 <= end; e += 4){
    int s0 = csr_src[e], s1 = csr_src[e+1], s2 = csr_src[e+2], s3 = csr_src[e+3];
    float4 a0 = h4[s0*32+lane], a1 = h4[s1*32+lane], a2 = h4[s2*32+lane], a3 = h4[s3*32+lane];
    acc.x += a0.x + a1.x + a2.x + a3.x;
    acc.y += a0.y + a1.y + a2.y + a3.y;
    acc.z += a0.z + a1.z + a2.z + a3.z;
    acc.w += a0.w + a1.w + a2.w + a3.w;
  }
  for (; e < end; ++e){
    float4 a = h4[csr_src[e]*32 + lane];
    acc.x += a.x; acc.y += a.y; acc.z += a.z; acc.w += a.w;
  }
  ((float4*)out)[row * 32 + lane] = acc;
}

// ---------- GEMM + bias + BN + ReLU ----------
// out[n][j] = relu( (A[n][:] @ W[:][j]) * sc[j] + sh[j] )
//   sc[j] = g[j] / sqrt(rv[j]+eps);  sh[j] = (bias[j]-rm[j])*sc[j] + be[j]
__device__ __forceinline__ void fma4(float4& a, float s, const float4& w){
  a.x = fmaf(s, w.x, a.x); a.y = fmaf(s, w.y, a.y);
  a.z = fmaf(s, w.z, a.z); a.w = fmaf(s, w.w, a.w);
}

__global__ __launch_bounds__(256) void k_gemm(
    const float* __restrict__ A,
    const float* __restrict__ W,      // fp32 [k][j] 128x128
    const float* __restrict__ bias,   // fp32 [128]
    const float* __restrict__ g,
    const float* __restrict__ be,
    const float* __restrict__ rm,
    const float* __restrict__ rv,
    float* __restrict__ outp)
{
  __shared__ float Wl[DD * DD];       // 64 KB fp32
  int t = threadIdx.x;
  {
    const float4* W4 = (const float4*)W;
    float4* Wl4 = (float4*)Wl;
    #pragma unroll
    for (int it = 0; it < 16; ++it) Wl4[it * 256 + t] = W4[it * 256 + t];
  }
  __syncthreads();

  int col4 = t & 31;          // columns col4*4 .. +3
  int rg = t >> 5;            // row group: rows blockIdx.x*32 + rg*4 .. +3
  int row0 = blockIdx.x * 32 + rg * 4;
  int r0 = min(row0 + 0, NN - 1);
  int r1 = min(row0 + 1, NN - 1);
  int r2 = min(row0 + 2, NN - 1);
  int r3 = min(row0 + 3, NN - 1);

  const float4* A4 = (const float4*)A;
  const float4* Wl4 = (const float4*)Wl;
  float4 acc0 = {0,0,0,0}, acc1 = {0,0,0,0}, acc2 = {0,0,0,0}, acc3 = {0,0,0,0};

  #pragma unroll 4
  for (int k4 = 0; k4 < 32; ++k4){
    float4 a0 = A4[r0 * 32 + k4];
    float4 a1 = A4[r1 * 32 + k4];
    float4 a2 = A4[r2 * 32 + k4];
    float4 a3 = A4[r3 * 32 + k4];
    float4 w0 = Wl4[(k4*4 + 0) * 32 + col4];
    float4 w1 = Wl4[(k4*4 + 1) * 32 + col4];
    float4 w2 = Wl4[(k4*4 + 2) * 32 + col4];
    float4 w3 = Wl4[(k4*4 + 3) * 32 + col4];
    fma4(acc0, a0.x, w0); fma4(acc0, a0.y, w1); fma4(acc0, a0.z, w2); fma4(acc0, a0.w, w3);
    fma4(acc1, a1.x, w0); fma4(acc1, a1.y, w1); fma4(acc1, a1.z, w2); fma4(acc1, a1.w, w3);
    fma4(acc2, a2.x, w0); fma4(acc2, a2.y, w1); fma4(acc2, a2.z, w2); fma4(acc2, a2.w, w3);
    fma4(acc3, a3.x, w0); fma4(acc3, a3.y, w1); fma4(acc3, a3.z, w2); fma4(acc3, a3.w, w3);
  }

  // epilogue: per-column scale/shift from bias+BN
  int j = col4 * 4;
  float sc[4], sh[4];
  #pragma unroll
  for (int c = 0; c < 4; ++c){
    float s = g[j+c] * rsqrtf(rv[j+c] + 1e-5f);
    sc[c] = s;
    sh[c] = fmaf(bias[j+c] - rm[j+c], s, be[j+c]);
  }
  float4 accs[4] = {acc0, acc1, acc2, acc3};
  #pragma unroll
  for (int r = 0; r < 4; ++r){
    int row = row0 + r;
    if (row < NN){
      float4 v;
      v.x = fmaxf(fmaf(accs[r].x, sc[0], sh[0]), 0.0f);
      v.y = fmaxf(fmaf(accs[r].y, sc[1], sh[1]), 0.0f);
      v.z = fmaxf(fmaf(accs[r].z, sc[2], sh[2]), 0.0f);
      v.w = fmaxf(fmaf(accs[r].w, sc[3], sh[3]), 0.0f);
      ((float4*)outp)[row * 32 + col4] = v;
    }
  }
}

// ---------- launch ----------
extern "C" void kernel_launch(void* const* d_in, const int* in_sizes, int n_in,
                              void* d_out, int out_size, void* d_ws, size_t ws_size,
                              hipStream_t stream) {
  const float* x  = (const float*)d_in[0];     // fp32 [NN,DD]
  const int* ei   = (const int*)d_in[1];       // int32 [2,NE]
  const float* W1 = (const float*)d_in[2];     // fp32 [NL,DD,DD]
  const float* b1 = (const float*)d_in[3];     // fp32 [NL,DD]
  const float* W2 = (const float*)d_in[4];
  const float* b2 = (const float*)d_in[5];
  const float* g  = (const float*)d_in[6];     // fp32 [NL,2,DD]
  const float* be = (const float*)d_in[7];
  const float* rm = (const float*)d_in[8];
  const float* rv = (const float*)d_in[9];

  const int* src = ei;
  const int* dst = ei + NE;

  // ws partition (bytes)
  char* w = (char*)d_ws;
  const size_t FB = (size_t)NN * DD * sizeof(float);           // 25,600,000
  float* bufA = (float*)w;            w += FB;
  float* bufB = (float*)w;            w += FB;
  float* bufC = (float*)w;            w += FB;
  int* counts = (int*)w;              w += 200192;
  int* offs   = (int*)w;              w += 200192;
  int* cursor = (int*)w;              w += 200192;
  int* bsum   = (int*)w;              w += 1024;
  int* csr_src= (int*)w;              w += (size_t)NE * sizeof(int);

  const int NBLK = (NN + 255) / 256;  // 196

  // CSR build (edge_index is the same for all layers)
  hipMemsetAsync(counts, 0, (size_t)NN * sizeof(int), stream);
  k_count<<<(NE + 255) / 256, 256, 0, stream>>>(dst, counts);
  k_scan1<<<NBLK, 256, 0, stream>>>(counts, offs, bsum);
  k_scan2<<<1, 256, 0, stream>>>(bsum, NBLK);
  k_scan3<<<NBLK, 256, 0, stream>>>(offs, bsum, cursor);
  k_fill<<<(NE + 255) / 256, 256, 0, stream>>>(src, dst, cursor, csr_src);

  const int GEMM_BLOCKS = (NN + 31) / 32;        // 1563
  const int AGG_BLOCKS  = (NN * 32 + 255) / 256; // 6250

  for (int i = 0; i < NL; ++i){
    const float* hin = (i == 0) ? x : bufA;
    k_agg<<<AGG_BLOCKS, 256, 0, stream>>>(hin, offs, counts, csr_src, bufB);

    const float* W1p = W1 + (size_t)i * DD * DD;
    const float* b1p = b1 + (size_t)i * DD;
    const float* W2p = W2 + (size_t)i * DD * DD;
    const float* b2p = b2 + (size_t)i * DD;
    const float* g0  = g  + (size_t)(i*2 + 0) * DD;
    const float* be0 = be + (size_t)(i*2 + 0) * DD;
    const float* rm0 = rm + (size_t)(i*2 + 0) * DD;
    const float* rv0 = rv + (size_t)(i*2 + 0) * DD;
    const float* g1  = g  + (size_t)(i*2 + 1) * DD;
    const float* be1 = be + (size_t)(i*2 + 1) * DD;
    const float* rm1 = rm + (size_t)(i*2 + 1) * DD;
    const float* rv1 = rv + (size_t)(i*2 + 1) * DD;

    k_gemm<<<GEMM_BLOCKS, 256, 0, stream>>>(bufB, W1p, b1p, g0, be0, rm0, rv0, bufC);
    float* out2 = (i == NL - 1) ? (float*)d_out : bufA;
    k_gemm<<<GEMM_BLOCKS, 256, 0, stream>>>(bufC, W2p, b2p, g1, be1, rm1, rv1, out2);
  }
}

// Round 3
// 435.701 us; speedup vs baseline: 1.3305x; 1.3305x over previous
//
#include <hip/hip_runtime.h>
#include <stdint.h>

#define NN 50000
#define NE 800000
#define DD 128
#define NL 3
#define PAD 136   // LDS row stride in bf16 elems: 272 B = 17*16 -> 16B aligned, 2-way-max bank alias (free)

typedef __attribute__((ext_vector_type(8))) short short8;
typedef __attribute__((ext_vector_type(4))) float f32x4;

// ---------- bf16 helpers ----------
__device__ __forceinline__ float b2f(unsigned short u){
  union { unsigned int i; float f; } v; v.i = ((unsigned int)u) << 16; return v.f;
}
__device__ __forceinline__ unsigned short f2b(float f){
  union { float f; unsigned int i; } v; v.f = f;
  unsigned int r = 0x7FFFu + ((v.i >> 16) & 1u);
  return (unsigned short)((v.i + r) >> 16);
}

// ---------- CSR build ----------
__global__ void k_count(const int* __restrict__ dst, int* __restrict__ counts){
  int e = blockIdx.x * 256 + threadIdx.x;
  if (e < NE) atomicAdd(&counts[dst[e]], 1);
}

__global__ void k_scan1(const int* __restrict__ counts, int* __restrict__ offs,
                        int* __restrict__ bsum){
  __shared__ int s[256];
  int t = threadIdx.x; int i = blockIdx.x * 256 + t;
  int v = (i < NN) ? counts[i] : 0;
  s[t] = v; __syncthreads();
  for (int d = 1; d < 256; d <<= 1){
    int x = (t >= d) ? s[t - d] : 0;
    __syncthreads();
    s[t] += x;
    __syncthreads();
  }
  if (i < NN) offs[i] = s[t] - v;
  if (t == 255) bsum[blockIdx.x] = s[255];
}

__global__ void k_scan2(int* __restrict__ bsum, int nblk){
  __shared__ int s[256];
  int t = threadIdx.x;
  int v = (t < nblk) ? bsum[t] : 0;
  s[t] = v; __syncthreads();
  for (int d = 1; d < 256; d <<= 1){
    int x = (t >= d) ? s[t - d] : 0;
    __syncthreads();
    s[t] += x;
    __syncthreads();
  }
  if (t < nblk) bsum[t] = s[t] - v;
}

__global__ void k_scan3(int* __restrict__ offs, const int* __restrict__ bsum,
                        int* __restrict__ cursor){
  int i = blockIdx.x * 256 + threadIdx.x;
  if (i < NN){
    int o = offs[i] + bsum[blockIdx.x];
    offs[i] = o;
    cursor[i] = o;
  }
}

__global__ void k_fill(const int* __restrict__ src, const int* __restrict__ dst,
                       int* __restrict__ cursor, int* __restrict__ csr_src){
  int e = blockIdx.x * 256 + threadIdx.x;
  if (e < NE){
    int d = dst[e];
    int p = atomicAdd(&cursor[d], 1);
    csr_src[p] = src[e];
  }
}

// ---------- x: fp32 -> bf16 shadow ----------
__global__ void k_cvt(const float* __restrict__ x, unsigned short* __restrict__ o){
  int i = blockIdx.x * 256 + threadIdx.x;   // float4 index, grid covers exactly NN*DD/4
  float4 f = ((const float4*)x)[i];
  ushort4 u; u.x = f2b(f.x); u.y = f2b(f.y); u.z = f2b(f.z); u.w = f2b(f.w);
  ((ushort4*)o)[i] = u;
}

// ---------- aggregate: out = hf[v] + sum over bf16 gather of neighbors ----------
__global__ __launch_bounds__(256) void k_agg(
    const unsigned short* __restrict__ hb,   // bf16 [NN][128] gather table
    const float* __restrict__ hf,            // fp32 [NN][128] self term
    const int* __restrict__ offs, const int* __restrict__ counts,
    const int* __restrict__ csr_src, float* __restrict__ out){
  int t = blockIdx.x * 256 + threadIdx.x;
  int row = t >> 5;
  int lane = t & 31;
  if (row >= NN) return;
  const ushort4* h4 = (const ushort4*)hb;    // 8B per lane -> 256B per row
  float4 acc = ((const float4*)hf)[row * 32 + lane];  // self (fp32, exact)
  int e = offs[row];
  int end = e + counts[row];
  for (; e + 4 <= end; e += 4){
    int s0 = csr_src[e], s1 = csr_src[e+1], s2 = csr_src[e+2], s3 = csr_src[e+3];
    ushort4 a0 = h4[s0*32+lane], a1 = h4[s1*32+lane], a2 = h4[s2*32+lane], a3 = h4[s3*32+lane];
    acc.x += b2f(a0.x) + b2f(a1.x) + b2f(a2.x) + b2f(a3.x);
    acc.y += b2f(a0.y) + b2f(a1.y) + b2f(a2.y) + b2f(a3.y);
    acc.z += b2f(a0.z) + b2f(a1.z) + b2f(a2.z) + b2f(a3.z);
    acc.w += b2f(a0.w) + b2f(a1.w) + b2f(a2.w) + b2f(a3.w);
  }
  for (; e < end; ++e){
    ushort4 a = h4[csr_src[e]*32 + lane];
    acc.x += b2f(a.x); acc.y += b2f(a.y); acc.z += b2f(a.z); acc.w += b2f(a.w);
  }
  ((float4*)out)[row * 32 + lane] = acc;
}

// ---------- fused MLP: gemm1 -> BN -> ReLU -> gemm2 -> BN -> ReLU ----------
// Split bf16 MFMA (hi+lo) for near-fp32 precision.
// Block: 512 thr = 8 waves, 128 rows. LDS: Whi,Wlo,Ahi,Alo (128xPAD u16 each) + sc/sh.
__device__ __forceinline__ void stage_w(const float* __restrict__ Wg,
    unsigned short* Whi, unsigned short* Wlo, int t){
  #pragma unroll
  for (int it = 0; it < 8; ++it){
    int idx4 = it * 512 + t;                 // 4096 float4 = 128x128
    int k = idx4 >> 5, j4 = (idx4 & 31) * 4;
    float4 w = ((const float4*)Wg)[idx4];
    float wv[4] = {w.x, w.y, w.z, w.w};
    #pragma unroll
    for (int c = 0; c < 4; ++c){
      unsigned short hi = f2b(wv[c]);
      Whi[(j4+c)*PAD + k] = hi;              // transposed: Wt[j][k]
      Wlo[(j4+c)*PAD + k] = f2b(wv[c] - b2f(hi));
    }
  }
}

__global__ __launch_bounds__(512) void k_mlp(
    const float* __restrict__ A,            // fp32 agg output [NN][128]
    const float* __restrict__ W1g, const float* __restrict__ b1g,
    const float* __restrict__ W2g, const float* __restrict__ b2g,
    const float* __restrict__ g0, const float* __restrict__ be0,
    const float* __restrict__ rm0, const float* __restrict__ rv0,
    const float* __restrict__ g1, const float* __restrict__ be1,
    const float* __restrict__ rm1, const float* __restrict__ rv1,
    float* __restrict__ outf,               // fp32 out (hf or d_out)
    unsigned short* __restrict__ outb,      // bf16 shadow for next agg
    int write_bf16)
{
  extern __shared__ char smem[];
  unsigned short* Whi = (unsigned short*)smem;       // 128*PAD u16 = 34816 B
  unsigned short* Wlo = Whi + DD*PAD;
  unsigned short* Ahi = Wlo + DD*PAD;
  unsigned short* Alo = Ahi + DD*PAD;
  float* sc1 = (float*)(Alo + DD*PAD);
  float* sh1 = sc1 + DD;
  float* sc2 = sh1 + DD;
  float* sh2 = sc2 + DD;

  int t = threadIdx.x;
  int base = blockIdx.x * DD;               // 128 rows per block

  if (t < DD){
    float s = g0[t] * rsqrtf(rv0[t] + 1e-5f);
    sc1[t] = s; sh1[t] = fmaf(b1g[t] - rm0[t], s, be0[t]);
  } else if (t < 2*DD){
    int j = t - DD;
    float s = g1[j] * rsqrtf(rv1[j] + 1e-5f);
    sc2[j] = s; sh2[j] = fmaf(b2g[j] - rm1[j], s, be1[j]);
  }

  stage_w(W1g, Whi, Wlo, t);

  // stage A tile, split hi/lo
  #pragma unroll
  for (int it = 0; it < 8; ++it){
    int idx = it * 512 + t;                 // 4096 float4 = 128 rows x 32
    int r = idx >> 5, k4 = idx & 31;
    int rg = base + r; if (rg > NN-1) rg = NN-1;
    float4 a = ((const float4*)A)[rg*32 + k4];
    float av[4] = {a.x, a.y, a.z, a.w};
    ushort4 hv, lv;
    unsigned short* hp = (unsigned short*)&hv;
    unsigned short* lp = (unsigned short*)&lv;
    #pragma unroll
    for (int c = 0; c < 4; ++c){
      unsigned short hi = f2b(av[c]);
      hp[c] = hi; lp[c] = f2b(av[c] - b2f(hi));
    }
    *(ushort4*)&Ahi[r*PAD + k4*4] = hv;
    *(ushort4*)&Alo[r*PAD + k4*4] = lv;
  }
  __syncthreads();

  int lane = t & 63;
  int wave = t >> 6;
  int l16 = lane & 15;
  int q = lane >> 4;
  int r0 = wave * 16;                       // this wave's 16 rows (block-local)

  // ---- gemm1 ----
  f32x4 acc[8];
  #pragma unroll
  for (int ct = 0; ct < 8; ++ct) acc[ct] = (f32x4){0.f,0.f,0.f,0.f};

  #pragma unroll
  for (int kc = 0; kc < 4; ++kc){
    short8 ah = *(const short8*)&Ahi[(r0+l16)*PAD + kc*32 + q*8];
    short8 al = *(const short8*)&Alo[(r0+l16)*PAD + kc*32 + q*8];
    #pragma unroll
    for (int ct = 0; ct < 8; ++ct){
      short8 bh = *(const short8*)&Whi[(ct*16+l16)*PAD + kc*32 + q*8];
      short8 bl = *(const short8*)&Wlo[(ct*16+l16)*PAD + kc*32 + q*8];
      acc[ct] = __builtin_amdgcn_mfma_f32_16x16x32_bf16(ah, bh, acc[ct], 0, 0, 0);
      acc[ct] = __builtin_amdgcn_mfma_f32_16x16x32_bf16(ah, bl, acc[ct], 0, 0, 0);
      acc[ct] = __builtin_amdgcn_mfma_f32_16x16x32_bf16(al, bh, acc[ct], 0, 0, 0);
    }
  }

  // h2 = relu(bn1(gemm1)), write split into own A rows (same-wave region, no sync needed)
  #pragma unroll
  for (int ct = 0; ct < 8; ++ct){
    int col = ct*16 + l16;
    float s = sc1[col], h = sh1[col];
    #pragma unroll
    for (int r = 0; r < 4; ++r){
      int row_l = r0 + q*4 + r;             // C/D layout: row=(lane>>4)*4+reg
      float v = fmaxf(fmaf(acc[ct][r], s, h), 0.0f);
      unsigned short hi = f2b(v);
      Ahi[row_l*PAD + col] = hi;
      Alo[row_l*PAD + col] = f2b(v - b2f(hi));
    }
  }

  __syncthreads();                          // all waves done reading W1
  stage_w(W2g, Whi, Wlo, t);
  __syncthreads();

  // ---- gemm2 ----
  f32x4 acc2[8];
  #pragma unroll
  for (int ct = 0; ct < 8; ++ct) acc2[ct] = (f32x4){0.f,0.f,0.f,0.f};

  #pragma unroll
  for (int kc = 0; kc < 4; ++kc){
    short8 ah = *(const short8*)&Ahi[(r0+l16)*PAD + kc*32 + q*8];
    short8 al = *(const short8*)&Alo[(r0+l16)*PAD + kc*32 + q*8];
    #pragma unroll
    for (int ct = 0; ct < 8; ++ct){
      short8 bh = *(const short8*)&Whi[(ct*16+l16)*PAD + kc*32 + q*8];
      short8 bl = *(const short8*)&Wlo[(ct*16+l16)*PAD + kc*32 + q*8];
      acc2[ct] = __builtin_amdgcn_mfma_f32_16x16x32_bf16(ah, bh, acc2[ct], 0, 0, 0);
      acc2[ct] = __builtin_amdgcn_mfma_f32_16x16x32_bf16(ah, bl, acc2[ct], 0, 0, 0);
      acc2[ct] = __builtin_amdgcn_mfma_f32_16x16x32_bf16(al, bh, acc2[ct], 0, 0, 0);
    }
  }

  // epilogue: BN2 + ReLU, store fp32 (+ optional bf16 shadow)
  #pragma unroll
  for (int ct = 0; ct < 8; ++ct){
    int col = ct*16 + l16;
    float s = sc2[col], h = sh2[col];
    #pragma unroll
    for (int r = 0; r < 4; ++r){
      int row_l = r0 + q*4 + r;
      int row_g = base + row_l;
      if (row_g < NN){
        float v = fmaxf(fmaf(acc2[ct][r], s, h), 0.0f);
        outf[row_g*DD + col] = v;
        if (write_bf16) outb[row_g*DD + col] = f2b(v);
      }
    }
  }
}

// ---------- launch ----------
extern "C" void kernel_launch(void* const* d_in, const int* in_sizes, int n_in,
                              void* d_out, int out_size, void* d_ws, size_t ws_size,
                              hipStream_t stream) {
  const float* x  = (const float*)d_in[0];
  const int* ei   = (const int*)d_in[1];
  const float* W1 = (const float*)d_in[2];
  const float* b1 = (const float*)d_in[3];
  const float* W2 = (const float*)d_in[4];
  const float* b2 = (const float*)d_in[5];
  const float* g  = (const float*)d_in[6];
  const float* be = (const float*)d_in[7];
  const float* rm = (const float*)d_in[8];
  const float* rv = (const float*)d_in[9];

  const int* src = ei;
  const int* dst = ei + NE;

  char* w = (char*)d_ws;
  const size_t FB = (size_t)NN * DD * sizeof(float);          // 25.6 MB
  const size_t HB = (size_t)NN * DD * sizeof(unsigned short); // 12.8 MB
  float* af          = (float*)w;          w += FB;   // agg output (fp32)
  float* hf          = (float*)w;          w += FB;   // fp32 h between layers
  unsigned short* hb = (unsigned short*)w; w += HB;   // bf16 gather shadow
  int* counts = (int*)w;  w += 200192;
  int* offs   = (int*)w;  w += 200192;
  int* cursor = (int*)w;  w += 200192;
  int* bsum   = (int*)w;  w += 1024;
  int* csr_src= (int*)w;  w += (size_t)NE * sizeof(int);

  const int NBLK = (NN + 255) / 256;

  // allow >64KB dynamic LDS for k_mlp (138.25 KB)
  const int MLP_LDS = 4 * DD * PAD * 2 + 4 * DD * 4;   // 141312... (W,A hi/lo + sc/sh)
  static bool attr_set = false;
  if (!attr_set){
    hipFuncSetAttribute((const void*)k_mlp,
        hipFuncAttributeMaxDynamicSharedMemorySize, MLP_LDS);
    attr_set = true;
  }

  // CSR build
  hipMemsetAsync(counts, 0, (size_t)NN * sizeof(int), stream);
  k_count<<<(NE + 255) / 256, 256, 0, stream>>>(dst, counts);
  k_scan1<<<NBLK, 256, 0, stream>>>(counts, offs, bsum);
  k_scan2<<<1, 256, 0, stream>>>(bsum, NBLK);
  k_scan3<<<NBLK, 256, 0, stream>>>(offs, bsum, cursor);
  k_fill<<<(NE + 255) / 256, 256, 0, stream>>>(src, dst, cursor, csr_src);

  // bf16 shadow of x
  k_cvt<<<NN * DD / 4 / 256, 256, 0, stream>>>(x, hb);

  const int AGG_BLOCKS = (NN * 32 + 255) / 256;  // 6250
  const int MLP_BLOCKS = (NN + DD - 1) / DD;     // 391

  for (int i = 0; i < NL; ++i){
    const float* self = (i == 0) ? x : hf;
    k_agg<<<AGG_BLOCKS, 256, 0, stream>>>(hb, self, offs, counts, csr_src, af);

    const float* W1p = W1 + (size_t)i * DD * DD;
    const float* b1p = b1 + (size_t)i * DD;
    const float* W2p = W2 + (size_t)i * DD * DD;
    const float* b2p = b2 + (size_t)i * DD;
    const float* g0  = g  + (size_t)(i*2 + 0) * DD;
    const float* be0 = be + (size_t)(i*2 + 0) * DD;
    const float* rm0 = rm + (size_t)(i*2 + 0) * DD;
    const float* rv0 = rv + (size_t)(i*2 + 0) * DD;
    const float* g1  = g  + (size_t)(i*2 + 1) * DD;
    const float* be1 = be + (size_t)(i*2 + 1) * DD;
    const float* rm1 = rm + (size_t)(i*2 + 1) * DD;
    const float* rv1 = rv + (size_t)(i*2 + 1) * DD;

    float* outf = (i == NL - 1) ? (float*)d_out : hf;
    int wb = (i == NL - 1) ? 0 : 1;
    k_mlp<<<MLP_BLOCKS, 512, MLP_LDS, stream>>>(af, W1p, b1p, W2p, b2p,
        g0, be0, rm0, rv0, g1, be1, rm1, rv1, outf, hb, wb);
  }
}